// Round 8
// baseline (540.379 us; speedup 1.0000x reference)
//
#include <hip/hip_runtime.h>
#include <math.h>

#define NC 1024
#define HID 256
#define NI 2

typedef _Float16 f16x8 __attribute__((ext_vector_type(8)));
typedef float f32x4 __attribute__((ext_vector_type(4)));
using gvoid = __attribute__((address_space(1))) const void;
using lvoid = __attribute__((address_space(3))) void;

#define LO_SCALE 2048.0f
#define LO_INV (1.0f / 2048.0f)

// ---------------------------------------------------------------------------
// Top-K gating, thread-per-element (block=1024). Matches jax.lax.top_k order.
// ---------------------------------------------------------------------------
__global__ __launch_bounds__(1024) void gate_kernel(const float* __restrict__ rg,
                                                    int* __restrict__ gidx,
                                                    float* __restrict__ gval)
{
    const int EDAT[5] = {8, 16, 64, 256, 1024};
    const int KDAT[5] = {4, 4, 32, 32, 256};
    const int OFF[5]  = {0, 8, 24, 88, 344};
    const int level = blockIdx.x, img = blockIdx.y;
    const int E = EDAT[level], K = KDAT[level], off = OFF[level];
    __shared__ float ga[1024];
    const float* src = rg + img * 1368 + off;
    const int t = threadIdx.x;
    if (t < E) ga[t] = src[t];
    __syncthreads();
    if (t < E) {
        const float v = ga[t];
        const float a = fabsf(v);
        int rank = 0;
#pragma unroll 8
        for (int j = 0; j < E; j++) {
            float aj = fabsf(ga[j]);
            rank += (aj > a) || (aj == a && j < t);
        }
        if (rank < K) {
            int base = (level * 2 + img) * 256;
            gidx[base + rank] = t;
            gval[base + rank] = v;
        }
    }
}

// ---------------------------------------------------------------------------
// Layer 0: x[i,c,h] = sum_k gv[k]*__sinf(30*(coords[c]·W0row + b0))
// ---------------------------------------------------------------------------
__global__ __launch_bounds__(256) void layer0_kernel(const float* __restrict__ coords,
                                                     const float* __restrict__ W0,
                                                     const float* __restrict__ b0,
                                                     const int* __restrict__ gidx,
                                                     const float* __restrict__ gval,
                                                     float* __restrict__ xout)
{
    const int c = blockIdx.x, img = blockIdx.y, h = threadIdx.x;
    __shared__ int gi[4];
    __shared__ float gv[4];
    if (h < 4) {
        int base = (0 * 2 + img) * 256;
        gi[h] = gidx[base + h];
        gv[h] = gval[base + h];
    }
    __syncthreads();
    const float c0 = coords[c * 2], c1 = coords[c * 2 + 1];
    float s = 0.f;
#pragma unroll
    for (int k = 0; k < 4; k++) {
        int row = h * 8 + gi[k];
        s += gv[k] * __sinf(30.f * (c0 * W0[row * 2] + c1 * W0[row * 2 + 1] + b0[row]));
    }
    xout[((size_t)img * NC + c) * HID + h] = s;
}

// ---------------------------------------------------------------------------
// x-pack: f32 x -> Ap f16 [img][16 mt][8 planes][64x64 swz]; planes 0-3 hi,
// 4-7 lo*2048. One block per (mt,img,sa) writes BOTH hi and lo (single read).
// ---------------------------------------------------------------------------
__global__ __launch_bounds__(256) void xpack_kernel(const float* __restrict__ x,
                                                    _Float16* __restrict__ Ap)
{
    const int mt = blockIdx.x, img = blockIdx.y, sa = blockIdx.z;  // sa 0..3
    const int t = threadIdx.x;
    const int c = t & 63, r0 = t >> 6;
    const float* xb = x + ((size_t)img * NC + mt * 64) * HID;
    _Float16* aph = Ap + ((size_t)(img * 16 + mt) * 8 + sa) * 4096;
    _Float16* apl = aph + 4 * 4096;
    const int kk = sa * 64 + c;
#pragma unroll
    for (int rr = 0; rr < 64; rr += 4) {
        int r = rr + r0;
        float v = xb[r * HID + kk];
        _Float16 h = (_Float16)v;
        int idx = r * 64 + (c ^ ((r & 7) << 3));
        aph[idx] = h;
        apl[idx] = (_Float16)((v - (float)h) * LO_SCALE);
    }
}

// ---------------------------------------------------------------------------
// W-pack: gather active rows (per img), hi+lo planes in one pass.
// Bp layout [img][ntile(64 rows)][8 planes][4096]; 0-3 hi, 4-7 lo*2048.
// ---------------------------------------------------------------------------
__global__ __launch_bounds__(256) void wpack_kernel(const float* __restrict__ W,
                                                    const float* __restrict__ bias,
                                                    const int* __restrict__ gidx,
                                                    const float* __restrict__ gval,
                                                    int level, int E, int lgK,
                                                    _Float16* __restrict__ Bp,
                                                    float* __restrict__ biasP,
                                                    float* __restrict__ gvP,
                                                    int ntiles)
{
    const int ntile = blockIdx.x, img = blockIdx.y, sa = blockIdx.z;  // sa 0..3
    const int t = threadIdx.x;
    const int N = ntiles * 64;
    __shared__ int wrowS[64];
    const int base = (level * 2 + img) * 256;
    if (t < 64) {
        int n = ntile * 64 + t;
        int dd = n >> lgK, k = n & ((1 << lgK) - 1);
        int wrow = dd * E + gidx[base + k];
        wrowS[t] = wrow;
        if (sa == 0) {
            biasP[img * N + n] = bias[wrow];
            gvP[img * N + n] = gval[base + k];
        }
    }
    __syncthreads();
    const int c = t & 63, r0 = t >> 6;
    const int kk = sa * 64 + c;
    _Float16* bph = Bp + ((size_t)(img * ntiles + ntile) * 8 + sa) * 4096;
    _Float16* bpl = bph + 4 * 4096;
#pragma unroll
    for (int rr = 0; rr < 64; rr += 4) {
        int r = rr + r0;
        float v = W[(size_t)wrowS[r] * HID + kk];
        _Float16 h = (_Float16)v;
        int idx = r * 64 + (c ^ ((r & 7) << 3));
        bph[idx] = h;
        bpl[idx] = (_Float16)((v - (float)h) * LO_SCALE);
    }
}

// ---------------------------------------------------------------------------
// Mid-layer MFMA GEMM, split-f16, XCD-swizzled flat grid.
// FUSED 4-phase schedule: each phase p stages the k-slice p of ALL FOUR
// planes {A-hi 8K | A-lo 8K | B-hi 16K | B-lo 16K} = 48KB, then runs 48
// MFMA/wave (hihi->acc, loA*hiB->accL, hiA*loB->accL). Next phase's loads
// are issued BEFORE the MFMA cluster (single buffer; safe after the mid
// barrier since all frags are in regs) so L2 latency hides under MFMA.
//   result = acc + accL/2048
// ---------------------------------------------------------------------------
template <int KGRP, int NNT>
__global__ __launch_bounds__(256, 3) void mid_mfma_kernel(const _Float16* __restrict__ Ap,
                                                          const _Float16* __restrict__ Bp,
                                                          const float* __restrict__ biasP,
                                                          const float* __restrict__ gvP,
                                                          float* __restrict__ x_out)
{
    constexpr int NNTX = NNT / 8;
    const int b = blockIdx.x;
    const int q = b & 7;           // XCD
    const int j = b >> 3;
    const int mt = j & 15;
    const int img = (j >> 4) & 1;
    const int nt = q * NNTX + (j >> 5);

    const int tid = threadIdx.x;
    const int wave = tid >> 6, lane = tid & 63;
    const int wm = wave & 1, wn = wave >> 1;
    const int l15 = lane & 15, lhi = lane >> 4;

    __shared__ __align__(16) char lds[49152];  // 48KB staging; epilogue S aliases
    float* S = (float*)lds;

    const int ntiles = NNT * 2;
    const int N = ntiles * 64;
    const _Float16* ag = Ap + ((size_t)(img * 16 + mt) * 8) * 4096;
    const _Float16* bg = Bp + ((size_t)(img * ntiles + nt * 2) * 8) * 4096;

    // stage k-slice p: 48 slots of 1KB; this wave does slots [wave*12, wave*12+12)
    auto stage = [&](int p) {
        const int s0 = wave * 12;
#pragma unroll
        for (int qq = 0; qq < 12; ++qq) {
            const int s = s0 + qq;
            const _Float16* g;
            if (s < 8) {
                g = ag + (size_t)p * 4096 + s * 512 + lane * 8;                       // A-hi
            } else if (s < 16) {
                g = ag + (size_t)(4 + p) * 4096 + (s - 8) * 512 + lane * 8;          // A-lo
            } else if (s < 32) {
                int s2 = s - 16;
                g = bg + (size_t)((s2 >> 3) * 8 + p) * 4096 + (s2 & 7) * 512 + lane * 8;      // B-hi
            } else {
                int s2 = s - 32;
                g = bg + (size_t)((s2 >> 3) * 8 + 4 + p) * 4096 + (s2 & 7) * 512 + lane * 8;  // B-lo
            }
            __builtin_amdgcn_global_load_lds((gvoid*)g, (lvoid*)(lds + s * 1024), 16, 0, 0);
        }
    };

    f32x4 acc[2][4], accL[2][4];
#pragma unroll
    for (int mi = 0; mi < 2; mi++)
#pragma unroll
        for (int ni = 0; ni < 4; ni++) { acc[mi][ni] = (f32x4)0.f; accL[mi][ni] = (f32x4)0.f; }

    stage(0);
    __syncthreads();  // implicit vmcnt(0) drain before s_barrier

#pragma unroll
    for (int p = 0; p < 4; ++p) {
        // ---- read all frags for this phase into regs (regions: 0 A-hi,
        //      8192 A-lo, 16384 B-hi, 32768 B-lo) ----
        f16x8 afh[2][2], afl[2][2];
#pragma unroll
        for (int ks = 0; ks < 2; ++ks)
#pragma unroll
            for (int mi = 0; mi < 2; ++mi) {
                int row = wm * 32 + mi * 16 + l15;
                int off = row * 128 + (((lhi + 4 * ks) ^ (row & 7)) * 16);
                afh[ks][mi] = *(const f16x8*)(lds + off);
                afl[ks][mi] = *(const f16x8*)(lds + 8192 + off);
            }
        f16x8 bfh[2][4], bfl[2][4];
#pragma unroll
        for (int ks = 0; ks < 2; ++ks)
#pragma unroll
            for (int ni = 0; ni < 4; ++ni) {
                int row = wn * 64 + ni * 16 + l15;
                int off = row * 128 + (((lhi + 4 * ks) ^ (row & 7)) * 16);
                bfh[ks][ni] = *(const f16x8*)(lds + 16384 + off);
                bfl[ks][ni] = *(const f16x8*)(lds + 32768 + off);
            }
        __syncthreads();            // drains lgkmcnt: all waves' reads in regs
        if (p < 3) stage(p + 1);    // issue next slice; latency hides under MFMA

        // ---- 48 MFMA ----
#pragma unroll
        for (int ks = 0; ks < 2; ++ks)
#pragma unroll
            for (int mi = 0; mi < 2; ++mi)
#pragma unroll
                for (int ni = 0; ni < 4; ++ni)
                    acc[mi][ni] = __builtin_amdgcn_mfma_f32_16x16x32_f16(afh[ks][mi], bfh[ks][ni],
                                                                         acc[mi][ni], 0, 0, 0);
#pragma unroll
        for (int ks = 0; ks < 2; ++ks)
#pragma unroll
            for (int mi = 0; mi < 2; ++mi)
#pragma unroll
                for (int ni = 0; ni < 4; ++ni)
                    accL[mi][ni] = __builtin_amdgcn_mfma_f32_16x16x32_f16(afl[ks][mi], bfh[ks][ni],
                                                                          accL[mi][ni], 0, 0, 0);
#pragma unroll
        for (int ks = 0; ks < 2; ++ks)
#pragma unroll
            for (int mi = 0; mi < 2; ++mi)
#pragma unroll
                for (int ni = 0; ni < 4; ++ni)
                    accL[mi][ni] = __builtin_amdgcn_mfma_f32_16x16x32_f16(afh[ks][mi], bfl[ks][ni],
                                                                          accL[mi][ni], 0, 0, 0);
        __syncthreads();            // drains vmcnt: stage(p+1) landed
    }

    // epilogue: combine hi/lo accumulators, sin + gate weight -> S
#pragma unroll
    for (int mi = 0; mi < 2; ++mi)
#pragma unroll
        for (int ni = 0; ni < 4; ++ni) {
            int n = wn * 64 + ni * 16 + l15;
            int gn = nt * 128 + n;
            float bv = biasP[img * N + gn];
            float gv = gvP[img * N + gn];
#pragma unroll
            for (int r = 0; r < 4; ++r) {
                int m = wm * 32 + mi * 16 + lhi * 4 + r;
                float val = acc[mi][ni][r] + accL[mi][ni][r] * LO_INV;
                S[m * 129 + n] = gv * __sinf(30.f * (val + bv));
            }
        }
    __syncthreads();

    float* xo = x_out + ((size_t)img * NC + mt * 64) * HID;
    if (KGRP == 32) {
        int m = tid >> 2, d = tid & 3;
        float s = 0.f;
#pragma unroll
        for (int jj = 0; jj < 32; ++jj) s += S[m * 129 + d * 32 + ((jj + d * 8) & 31)];
        xo[m * HID + nt * 4 + d] = s;
    } else {
#pragma unroll
        for (int rep = 0; rep < 8; ++rep) {
            int idx = rep * 256 + tid;
            int m = idx >> 5, d = idx & 31;
            const float* Sp = S + m * 129 + d * 4;
            xo[m * HID + nt * 32 + d] = Sp[0] + Sp[1] + Sp[2] + Sp[3];
        }
    }
}

// ---------------------------------------------------------------------------
// Layer 4 precombine: gates applied linearly -> fold into weights once:
//   Weff[i,d,:] = sum_e gv[e]*W4[d*1024+gidx[e],:],  beff[i,d] = sum_e gv[e]*b4
// ---------------------------------------------------------------------------
__global__ __launch_bounds__(256) void l4combine_kernel(const float* __restrict__ W4,
                                                        const float* __restrict__ b4,
                                                        const int* __restrict__ gidx,
                                                        const float* __restrict__ gval,
                                                        float* __restrict__ Weff,
                                                        float* __restrict__ beff)
{
    const int d = blockIdx.x, img = blockIdx.y;
    const int t = threadIdx.x;
    const int base = (4 * 2 + img) * 256;
    __shared__ int rows[256];
    __shared__ float gs[256];
    __shared__ float bred[256];
    int e = gidx[base + t];
    float g = gval[base + t];
    rows[t] = (d * 1024 + e) * 256;
    gs[t] = g;
    bred[t] = g * b4[d * 1024 + e];
    __syncthreads();
    float acc = 0.f;
#pragma unroll 4
    for (int k = 0; k < 256; ++k)
        acc = fmaf(gs[k], W4[(size_t)rows[k] + t], acc);
    Weff[(img * 3 + d) * 256 + t] = acc;
    for (int s = 128; s > 0; s >>= 1) {
        if (t < s) bred[t] += bred[t + s];
        __syncthreads();
    }
    if (t == 0) beff[img * 3 + d] = bred[0];
}

// ---------------------------------------------------------------------------
// Layer 4 apply: out[i,c,d] = x[i,c,:]·Weff[i,d,:] + beff[i,d]
// ---------------------------------------------------------------------------
__global__ __launch_bounds__(256) void l4apply_kernel(const float* __restrict__ x_in,
                                                      const float* __restrict__ Weff,
                                                      const float* __restrict__ beff,
                                                      float* __restrict__ out)
{
    const int img = blockIdx.y;
    const int c = blockIdx.x * 256 + threadIdx.x;
    __shared__ float ws[3][256];
    __shared__ float bs[3];
    const int t = threadIdx.x;
    if (t < 192) {
        int d = t / 64, k4 = t % 64;
        *(float4*)&ws[d][k4 * 4] = *(const float4*)(Weff + (img * 3 + d) * 256 + k4 * 4);
    }
    if (t < 3) bs[t] = beff[img * 3 + t];
    __syncthreads();
    const float* xb = x_in + ((size_t)img * NC + c) * HID;
    float a0 = 0.f, a1 = 0.f, a2 = 0.f;
#pragma unroll 4
    for (int k = 0; k < 256; k += 4) {
        const float4 xv = *(const float4*)(xb + k);
        const float4 w0 = *(const float4*)&ws[0][k];
        const float4 w1 = *(const float4*)&ws[1][k];
        const float4 w2 = *(const float4*)&ws[2][k];
        a0 += xv.x * w0.x + xv.y * w0.y + xv.z * w0.z + xv.w * w0.w;
        a1 += xv.x * w1.x + xv.y * w1.y + xv.z * w1.z + xv.w * w1.w;
        a2 += xv.x * w2.x + xv.y * w2.y + xv.z * w2.z + xv.w * w2.w;
    }
    float* o = out + ((size_t)img * NC + c) * 3;
    o[0] = a0 + bs[0];
    o[1] = a1 + bs[1];
    o[2] = a2 + bs[2];
}

// ---------------------------------------------------------------------------
extern "C" void kernel_launch(void* const* d_in, const int* in_sizes, int n_in,
                              void* d_out, int out_size, void* d_ws, size_t ws_size,
                              hipStream_t stream)
{
    const float* rg     = (const float*)d_in[0];
    const float* coords = (const float*)d_in[1];
    const float* W0 = (const float*)d_in[2];
    const float* b0 = (const float*)d_in[3];
    const float* W1 = (const float*)d_in[4];
    const float* b1 = (const float*)d_in[5];
    const float* W2 = (const float*)d_in[6];
    const float* b2 = (const float*)d_in[7];
    const float* W3 = (const float*)d_in[8];
    const float* b3 = (const float*)d_in[9];
    const float* W4 = (const float*)d_in[10];
    const float* b4 = (const float*)d_in[11];
    float* out = (float*)d_out;

    char* ws = (char*)d_ws;
    int*      gidx  = (int*)ws;                                // 10240 B
    float*    gval  = (float*)(ws + 10240);                    // 10240 B
    float*    xA    = (float*)(ws + 20480);                    // 2 MiB
    float*    xB    = (float*)(ws + 2117632);                  // 2 MiB
    _Float16* Ap    = (_Float16*)(ws + 4214784);               // 2 MiB
    _Float16* Bp    = (_Float16*)(ws + 6311936);               // 16 MiB
    float*    biasP = (float*)(ws + 23089152);                 // 64 KiB
    float*    gvP   = (float*)(ws + 23154688);                 // 64 KiB
    float*    Weff  = (float*)(ws + 23220224);                 // 6 KiB
    float*    beff  = (float*)(ws + 23228416);                 // 24 B

    gate_kernel<<<dim3(5, 2), 1024, 0, stream>>>(rg, gidx, gval);
    l4combine_kernel<<<dim3(3, 2), 256, 0, stream>>>(W4, b4, gidx, gval, Weff, beff);
    layer0_kernel<<<dim3(NC, NI), 256, 0, stream>>>(coords, W0, b0, gidx, gval, xA);

    // level 1: E=16, K=4, N=1024 (8 nt blocks)
    xpack_kernel<<<dim3(16, 2, 4), 256, 0, stream>>>(xA, Ap);
    wpack_kernel<<<dim3(16, 2, 4), 256, 0, stream>>>(W1, b1, gidx, gval, 1, 16, 2, Bp, biasP, gvP, 16);
    mid_mfma_kernel<4, 8><<<256, 256, 0, stream>>>(Ap, Bp, biasP, gvP, xB);

    // level 2: E=64, K=32, N=8192 (64 nt blocks)
    xpack_kernel<<<dim3(16, 2, 4), 256, 0, stream>>>(xB, Ap);
    wpack_kernel<<<dim3(128, 2, 4), 256, 0, stream>>>(W2, b2, gidx, gval, 2, 64, 5, Bp, biasP, gvP, 128);
    mid_mfma_kernel<32, 64><<<2048, 256, 0, stream>>>(Ap, Bp, biasP, gvP, xA);

    // level 3: E=256, K=32, N=8192
    xpack_kernel<<<dim3(16, 2, 4), 256, 0, stream>>>(xA, Ap);
    wpack_kernel<<<dim3(128, 2, 4), 256, 0, stream>>>(W3, b3, gidx, gval, 3, 256, 5, Bp, biasP, gvP, 128);
    mid_mfma_kernel<32, 64><<<2048, 256, 0, stream>>>(Ap, Bp, biasP, gvP, xB);

    l4apply_kernel<<<dim3(4, 2), 256, 0, stream>>>(xB, Weff, beff, out);
}

// Round 9
// 312.724 us; speedup vs baseline: 1.7280x; 1.7280x over previous
//
#include <hip/hip_runtime.h>
#include <math.h>

#define NC 1024
#define HID 256
#define NI 2

typedef _Float16 f16x8 __attribute__((ext_vector_type(8)));
typedef float f32x4 __attribute__((ext_vector_type(4)));
using gvoid = __attribute__((address_space(1))) const void;
using lvoid = __attribute__((address_space(3))) void;

#define LO_SCALE 2048.0f
#define LO_INV (1.0f / 2048.0f)

// ---------------------------------------------------------------------------
// Top-K gating, thread-per-element (block=1024). Matches jax.lax.top_k order.
// ---------------------------------------------------------------------------
__global__ __launch_bounds__(1024) void gate_kernel(const float* __restrict__ rg,
                                                    int* __restrict__ gidx,
                                                    float* __restrict__ gval)
{
    const int EDAT[5] = {8, 16, 64, 256, 1024};
    const int KDAT[5] = {4, 4, 32, 32, 256};
    const int OFF[5]  = {0, 8, 24, 88, 344};
    const int level = blockIdx.x, img = blockIdx.y;
    const int E = EDAT[level], K = KDAT[level], off = OFF[level];
    __shared__ float ga[1024];
    const float* src = rg + img * 1368 + off;
    const int t = threadIdx.x;
    if (t < E) ga[t] = src[t];
    __syncthreads();
    if (t < E) {
        const float v = ga[t];
        const float a = fabsf(v);
        int rank = 0;
#pragma unroll 8
        for (int j = 0; j < E; j++) {
            float aj = fabsf(ga[j]);
            rank += (aj > a) || (aj == a && j < t);
        }
        if (rank < K) {
            int base = (level * 2 + img) * 256;
            gidx[base + rank] = t;
            gval[base + rank] = v;
        }
    }
}

// ---------------------------------------------------------------------------
// Layer 0: x[i,c,h] = sum_k gv[k]*__sinf(30*(coords[c]·W0row + b0))
// ---------------------------------------------------------------------------
__global__ __launch_bounds__(256) void layer0_kernel(const float* __restrict__ coords,
                                                     const float* __restrict__ W0,
                                                     const float* __restrict__ b0,
                                                     const int* __restrict__ gidx,
                                                     const float* __restrict__ gval,
                                                     float* __restrict__ xout)
{
    const int c = blockIdx.x, img = blockIdx.y, h = threadIdx.x;
    __shared__ int gi[4];
    __shared__ float gv[4];
    if (h < 4) {
        int base = (0 * 2 + img) * 256;
        gi[h] = gidx[base + h];
        gv[h] = gval[base + h];
    }
    __syncthreads();
    const float c0 = coords[c * 2], c1 = coords[c * 2 + 1];
    float s = 0.f;
#pragma unroll
    for (int k = 0; k < 4; k++) {
        int row = h * 8 + gi[k];
        s += gv[k] * __sinf(30.f * (c0 * W0[row * 2] + c1 * W0[row * 2 + 1] + b0[row]));
    }
    xout[((size_t)img * NC + c) * HID + h] = s;
}

// ---------------------------------------------------------------------------
// x-pack: f32 x -> Ap f16 [img][16 mt][8 planes][64x64 swz]; planes 0-3 hi,
// 4-7 lo*2048. Swizzle idx = r*64 + (c ^ ((r&7)<<3)).
// ---------------------------------------------------------------------------
__global__ __launch_bounds__(256) void xpack_kernel(const float* __restrict__ x,
                                                    _Float16* __restrict__ Ap)
{
    const int mt = blockIdx.x, img = blockIdx.y, sa = blockIdx.z;  // sa 0..3
    const int t = threadIdx.x;
    const int c = t & 63, r0 = t >> 6;
    const float* xb = x + ((size_t)img * NC + mt * 64) * HID;
    _Float16* aph = Ap + ((size_t)(img * 16 + mt) * 8 + sa) * 4096;
    _Float16* apl = aph + 4 * 4096;
    const int kk = sa * 64 + c;
#pragma unroll
    for (int rr = 0; rr < 64; rr += 4) {
        int r = rr + r0;
        float v = xb[r * HID + kk];
        _Float16 h = (_Float16)v;
        int idx = r * 64 + (c ^ ((r & 7) << 3));
        aph[idx] = h;
        apl[idx] = (_Float16)((v - (float)h) * LO_SCALE);
    }
}

// ---------------------------------------------------------------------------
// W-pack: gather active rows (per img), hi+lo planes in one pass.
// Bp layout [img][ntile(64 rows)][8 planes][4096]; 0-3 hi, 4-7 lo*2048.
// ---------------------------------------------------------------------------
__global__ __launch_bounds__(256) void wpack_kernel(const float* __restrict__ W,
                                                    const float* __restrict__ bias,
                                                    const int* __restrict__ gidx,
                                                    const float* __restrict__ gval,
                                                    int level, int E, int lgK,
                                                    _Float16* __restrict__ Bp,
                                                    float* __restrict__ biasP,
                                                    float* __restrict__ gvP,
                                                    int ntiles)
{
    const int ntile = blockIdx.x, img = blockIdx.y, sa = blockIdx.z;  // sa 0..3
    const int t = threadIdx.x;
    const int N = ntiles * 64;
    __shared__ int wrowS[64];
    const int base = (level * 2 + img) * 256;
    if (t < 64) {
        int n = ntile * 64 + t;
        int dd = n >> lgK, k = n & ((1 << lgK) - 1);
        int wrow = dd * E + gidx[base + k];
        wrowS[t] = wrow;
        if (sa == 0) {
            biasP[img * N + n] = bias[wrow];
            gvP[img * N + n] = gval[base + k];
        }
    }
    __syncthreads();
    const int c = t & 63, r0 = t >> 6;
    const int kk = sa * 64 + c;
    _Float16* bph = Bp + ((size_t)(img * ntiles + ntile) * 8 + sa) * 4096;
    _Float16* bpl = bph + 4 * 4096;
#pragma unroll
    for (int rr = 0; rr < 64; rr += 4) {
        int r = rr + r0;
        float v = W[(size_t)wrowS[r] * HID + kk];
        _Float16 h = (_Float16)v;
        int idx = r * 64 + (c ^ ((r & 7) << 3));
        bph[idx] = h;
        bpl[idx] = (_Float16)((v - (float)h) * LO_SCALE);
    }
}

// ---------------------------------------------------------------------------
// Mid-layer MFMA GEMM, split-f16, XCD-swizzled flat grid.
// 128x128 block, 4 waves of 64x64 (3:1 MFMA:ds_read vs old 1.33:1).
// 4 phases (k=64 slice each): stage ALL FOUR planes of next slice into the
// other 64KB buffer (each wave stages its own 16KB region: wave0 A-hi,
// wave1 A-lo, wave2 B-hi, wave3 B-lo), then 2 ks x {16 hh, 16 lh, 16 hl}.
//   result = acc + accL/2048
// Schedule per phase (R7-proven): vmcnt(0); barrier; stage(p+1, other buf);
// ds_read frags from cur buf; 96 MFMA.  LDS 128KB -> 1 block/CU;
// launch_bounds(256,1) so ~210 VGPR allocs WITHOUT spilling (R8 lesson:
// WRITE_SIZE 309MB was scratch spill from the (256,3) cap).
// ---------------------------------------------------------------------------
template <int KGRP, int NTB>
__global__ __launch_bounds__(256, 1) void mid_mfma_kernel(const _Float16* __restrict__ Ap,
                                                          const _Float16* __restrict__ Bp,
                                                          const float* __restrict__ biasP,
                                                          const float* __restrict__ gvP,
                                                          float* __restrict__ x_out)
{
    constexpr int NTBX = NTB / 8;
    const int b = blockIdx.x;
    const int q = b & 7;            // XCD
    const int j = b >> 3;
    const int mtp = j & 7;          // m-pair tile (128 rows)
    const int img = (j >> 3) & 1;
    const int ntl = j >> 4;         // local 128-col tile within XCD stripe
    const int nt = q * NTBX + ntl;  // global 128-col tile

    const int tid = threadIdx.x;
    const int wave = tid >> 6, lane = tid & 63;
    const int wm = wave & 1, wn = wave >> 1;
    const int l15 = lane & 15, lhi = lane >> 4;

    __shared__ __align__(16) char lds[131072];  // 2 x 64KB; epilogue S aliases
    float* S = (float*)lds;                     // [128][129] f32 = 66KB

    const int ntiles = NTB * 2;
    const int N = NTB * 128;
    const _Float16* ag = Ap + ((size_t)(img * 16 + mtp * 2) * 8) * 4096;
    const _Float16* bg = Bp + ((size_t)(img * ntiles + nt * 2) * 8) * 4096;

    // wave r: 0=A-hi, 1=A-lo, 2=B-hi, 3=B-lo; each stages 16 x 1KB slots.
    const _Float16* sbase = (wave & 2) ? bg : ag;
    const int planeAdd = (wave & 1) ? 4 : 0;    // lo planes at +4
    auto stage = [&](int bufoff, int p) {
#pragma unroll
        for (int qq = 0; qq < 16; ++qq) {
            const _Float16* g = sbase + (size_t)(qq >> 3) * 32768
                              + (planeAdd + p) * 4096 + (qq & 7) * 512 + lane * 8;
            __builtin_amdgcn_global_load_lds((gvoid*)g,
                (lvoid*)(lds + bufoff + wave * 16384 + qq * 1024), 16, 0, 0);
        }
    };

    f32x4 acc[4][4], accL[4][4];
#pragma unroll
    for (int mi = 0; mi < 4; mi++)
#pragma unroll
        for (int ni = 0; ni < 4; ni++) { acc[mi][ni] = (f32x4)0.f; accL[mi][ni] = (f32x4)0.f; }

    stage(0, 0);  // prologue

#pragma unroll
    for (int p = 0; p < 4; ++p) {
        const int cur = (p & 1) * 65536;
        asm volatile("s_waitcnt vmcnt(0)" ::: "memory");
        __syncthreads();                        // slice p landed; prev reads done
        if (p < 3) stage(65536 - cur, p + 1);   // overlap loads with reads+MFMA

#pragma unroll
        for (int ks = 0; ks < 2; ++ks) {
            f16x8 ah[4], al[4], bh[4], bl[4];
#pragma unroll
            for (int mi = 0; mi < 4; ++mi) {
                int row = wm * 64 + mi * 16 + l15;
                int off = (row >> 6) * 8192 + (row & 63) * 128
                        + (((lhi + 4 * ks) ^ (row & 7)) * 16);
                ah[mi] = *(const f16x8*)(lds + cur + off);
                al[mi] = *(const f16x8*)(lds + cur + 16384 + off);
            }
#pragma unroll
            for (int ni = 0; ni < 4; ++ni) {
                int row = wn * 64 + ni * 16 + l15;
                int off = (row >> 6) * 8192 + (row & 63) * 128
                        + (((lhi + 4 * ks) ^ (row & 7)) * 16);
                bh[ni] = *(const f16x8*)(lds + cur + 32768 + off);
                bl[ni] = *(const f16x8*)(lds + cur + 49152 + off);
            }
#pragma unroll
            for (int mi = 0; mi < 4; ++mi)
#pragma unroll
                for (int ni = 0; ni < 4; ++ni)
                    acc[mi][ni] = __builtin_amdgcn_mfma_f32_16x16x32_f16(ah[mi], bh[ni],
                                                                         acc[mi][ni], 0, 0, 0);
#pragma unroll
            for (int mi = 0; mi < 4; ++mi)
#pragma unroll
                for (int ni = 0; ni < 4; ++ni)
                    accL[mi][ni] = __builtin_amdgcn_mfma_f32_16x16x32_f16(al[mi], bh[ni],
                                                                          accL[mi][ni], 0, 0, 0);
#pragma unroll
            for (int mi = 0; mi < 4; ++mi)
#pragma unroll
                for (int ni = 0; ni < 4; ++ni)
                    accL[mi][ni] = __builtin_amdgcn_mfma_f32_16x16x32_f16(ah[mi], bl[ni],
                                                                          accL[mi][ni], 0, 0, 0);
        }
    }
    __syncthreads();

    // epilogue: combine hi/lo, sin + gate weight -> S[128][129]
#pragma unroll
    for (int mi = 0; mi < 4; ++mi)
#pragma unroll
        for (int ni = 0; ni < 4; ++ni) {
            int n = wn * 64 + ni * 16 + l15;
            int gn = nt * 128 + n;
            float bv = biasP[img * N + gn];
            float gv = gvP[img * N + gn];
#pragma unroll
            for (int r = 0; r < 4; ++r) {
                int m = wm * 64 + mi * 16 + lhi * 4 + r;
                float val = acc[mi][ni][r] + accL[mi][ni][r] * LO_INV;
                S[m * 129 + n] = gv * __sinf(30.f * (val + bv));
            }
        }
    __syncthreads();

    float* xo = x_out + ((size_t)img * NC + mtp * 128) * HID;
    if (KGRP == 32) {
        // 128 rows x 4 d-groups of 32 cols -> 512 outputs, 2 per thread
#pragma unroll
        for (int rep = 0; rep < 2; ++rep) {
            int idx = rep * 256 + tid;
            int m = idx >> 2, d = idx & 3;
            float s = 0.f;
#pragma unroll
            for (int jj = 0; jj < 32; ++jj) s += S[m * 129 + d * 32 + ((jj + d * 8) & 31)];
            xo[m * HID + nt * 4 + d] = s;
        }
    } else {
        // KGRP==4: 128 rows x 32 d-groups of 4 cols -> 4096 outputs, 16/thread
#pragma unroll
        for (int rep = 0; rep < 16; ++rep) {
            int idx = rep * 256 + tid;
            int m = idx >> 5, dl = idx & 31;
            const float* Sp = S + m * 129 + dl * 4;
            xo[m * HID + nt * 32 + dl] = Sp[0] + Sp[1] + Sp[2] + Sp[3];
        }
    }
}

// ---------------------------------------------------------------------------
// Layer 4 precombine: gates applied linearly -> fold into weights once:
//   Weff[i,d,:] = sum_e gv[e]*W4[d*1024+gidx[e],:],  beff[i,d] = sum_e gv[e]*b4
// ---------------------------------------------------------------------------
__global__ __launch_bounds__(256) void l4combine_kernel(const float* __restrict__ W4,
                                                        const float* __restrict__ b4,
                                                        const int* __restrict__ gidx,
                                                        const float* __restrict__ gval,
                                                        float* __restrict__ Weff,
                                                        float* __restrict__ beff)
{
    const int d = blockIdx.x, img = blockIdx.y;
    const int t = threadIdx.x;
    const int base = (4 * 2 + img) * 256;
    __shared__ int rows[256];
    __shared__ float gs[256];
    __shared__ float bred[256];
    int e = gidx[base + t];
    float g = gval[base + t];
    rows[t] = (d * 1024 + e) * 256;
    gs[t] = g;
    bred[t] = g * b4[d * 1024 + e];
    __syncthreads();
    float acc = 0.f;
#pragma unroll 4
    for (int k = 0; k < 256; ++k)
        acc = fmaf(gs[k], W4[(size_t)rows[k] + t], acc);
    Weff[(img * 3 + d) * 256 + t] = acc;
    for (int s = 128; s > 0; s >>= 1) {
        if (t < s) bred[t] += bred[t + s];
        __syncthreads();
    }
    if (t == 0) beff[img * 3 + d] = bred[0];
}

// ---------------------------------------------------------------------------
// Layer 4 apply: out[i,c,d] = x[i,c,:]·Weff[i,d,:] + beff[i,d]
// ---------------------------------------------------------------------------
__global__ __launch_bounds__(256) void l4apply_kernel(const float* __restrict__ x_in,
                                                      const float* __restrict__ Weff,
                                                      const float* __restrict__ beff,
                                                      float* __restrict__ out)
{
    const int img = blockIdx.y;
    const int c = blockIdx.x * 256 + threadIdx.x;
    __shared__ float ws[3][256];
    __shared__ float bs[3];
    const int t = threadIdx.x;
    if (t < 192) {
        int d = t / 64, k4 = t % 64;
        *(float4*)&ws[d][k4 * 4] = *(const float4*)(Weff + (img * 3 + d) * 256 + k4 * 4);
    }
    if (t < 3) bs[t] = beff[img * 3 + t];
    __syncthreads();
    const float* xb = x_in + ((size_t)img * NC + c) * HID;
    float a0 = 0.f, a1 = 0.f, a2 = 0.f;
#pragma unroll 4
    for (int k = 0; k < 256; k += 4) {
        const float4 xv = *(const float4*)(xb + k);
        const float4 w0 = *(const float4*)&ws[0][k];
        const float4 w1 = *(const float4*)&ws[1][k];
        const float4 w2 = *(const float4*)&ws[2][k];
        a0 += xv.x * w0.x + xv.y * w0.y + xv.z * w0.z + xv.w * w0.w;
        a1 += xv.x * w1.x + xv.y * w1.y + xv.z * w1.z + xv.w * w1.w;
        a2 += xv.x * w2.x + xv.y * w2.y + xv.z * w2.z + xv.w * w2.w;
    }
    float* o = out + ((size_t)img * NC + c) * 3;
    o[0] = a0 + bs[0];
    o[1] = a1 + bs[1];
    o[2] = a2 + bs[2];
}

// ---------------------------------------------------------------------------
extern "C" void kernel_launch(void* const* d_in, const int* in_sizes, int n_in,
                              void* d_out, int out_size, void* d_ws, size_t ws_size,
                              hipStream_t stream)
{
    const float* rg     = (const float*)d_in[0];
    const float* coords = (const float*)d_in[1];
    const float* W0 = (const float*)d_in[2];
    const float* b0 = (const float*)d_in[3];
    const float* W1 = (const float*)d_in[4];
    const float* b1 = (const float*)d_in[5];
    const float* W2 = (const float*)d_in[6];
    const float* b2 = (const float*)d_in[7];
    const float* W3 = (const float*)d_in[8];
    const float* b3 = (const float*)d_in[9];
    const float* W4 = (const float*)d_in[10];
    const float* b4 = (const float*)d_in[11];
    float* out = (float*)d_out;

    char* ws = (char*)d_ws;
    int*      gidx  = (int*)ws;                                // 10240 B
    float*    gval  = (float*)(ws + 10240);                    // 10240 B
    float*    xA    = (float*)(ws + 20480);                    // 2 MiB
    float*    xB    = (float*)(ws + 2117632);                  // 2 MiB
    _Float16* Ap    = (_Float16*)(ws + 4214784);               // 2 MiB
    _Float16* Bp    = (_Float16*)(ws + 6311936);               // 16 MiB
    float*    biasP = (float*)(ws + 23089152);                 // 64 KiB
    float*    gvP   = (float*)(ws + 23154688);                 // 64 KiB
    float*    Weff  = (float*)(ws + 23220224);                 // 6 KiB
    float*    beff  = (float*)(ws + 23228416);                 // 24 B

    gate_kernel<<<dim3(5, 2), 1024, 0, stream>>>(rg, gidx, gval);
    l4combine_kernel<<<dim3(3, 2), 256, 0, stream>>>(W4, b4, gidx, gval, Weff, beff);
    layer0_kernel<<<dim3(NC, NI), 256, 0, stream>>>(coords, W0, b0, gidx, gval, xA);

    // level 1: E=16, K=4, N=1024 (NTB=8 -> 128 blocks)
    xpack_kernel<<<dim3(16, 2, 4), 256, 0, stream>>>(xA, Ap);
    wpack_kernel<<<dim3(16, 2, 4), 256, 0, stream>>>(W1, b1, gidx, gval, 1, 16, 2, Bp, biasP, gvP, 16);
    mid_mfma_kernel<4, 8><<<128, 256, 0, stream>>>(Ap, Bp, biasP, gvP, xB);

    // level 2: E=64, K=32, N=8192 (NTB=64 -> 1024 blocks)
    xpack_kernel<<<dim3(16, 2, 4), 256, 0, stream>>>(xB, Ap);
    wpack_kernel<<<dim3(128, 2, 4), 256, 0, stream>>>(W2, b2, gidx, gval, 2, 64, 5, Bp, biasP, gvP, 128);
    mid_mfma_kernel<32, 64><<<1024, 256, 0, stream>>>(Ap, Bp, biasP, gvP, xA);

    // level 3: E=256, K=32, N=8192
    xpack_kernel<<<dim3(16, 2, 4), 256, 0, stream>>>(xA, Ap);
    wpack_kernel<<<dim3(128, 2, 4), 256, 0, stream>>>(W3, b3, gidx, gval, 3, 256, 5, Bp, biasP, gvP, 128);
    mid_mfma_kernel<32, 64><<<1024, 256, 0, stream>>>(Ap, Bp, biasP, gvP, xB);

    l4apply_kernel<<<dim3(4, 2), 256, 0, stream>>>(xB, Weff, beff, out);
}

// Round 11
// 312.448 us; speedup vs baseline: 1.7295x; 1.0009x over previous
//
#include <hip/hip_runtime.h>
#include <math.h>

#define NC 1024
#define HID 256
#define NI 2

typedef _Float16 f16x8 __attribute__((ext_vector_type(8)));
typedef float f32x4 __attribute__((ext_vector_type(4)));
using gvoid = __attribute__((address_space(1))) const void;
using lvoid = __attribute__((address_space(3))) void;

#define LO_SCALE 2048.0f
#define LO_INV (1.0f / 2048.0f)

// ---- workspace offsets (bytes) ----
#define OFF_GIDX  0          // 10240
#define OFF_GVAL  10240      // 10240
#define OFF_B1    20480      // 8192
#define OFF_G1    28672      // 8192
#define OFF_B2    36864      // 65536
#define OFF_G2    102400     // 65536
#define OFF_B3    167936     // 65536
#define OFF_G3    233472     // 65536
#define OFF_WEFF  299008     // 6144
#define OFF_BEFF  305152     // pad to 307200
#define OFF_APA   307200     // 2 MiB packed x (levels use ping-pong)
#define OFF_APB   (OFF_APA + 2097152)
#define OFF_BP1   (OFF_APB + 2097152)   // level1 B; REUSED as f32 xB after mid3
#define OFF_BP23  (OFF_BP1 + 2097152)   // 16 MiB, shared by level2 then level3

// ---------------------------------------------------------------------------
// pack_store: f32 value -> hi/lo f16 planes of the pre-swizzled tile layout
// Ap[img][mt][plane][64x64], plane = h>>6 (hi), +4 (lo); idx r*64 + (c^((r&7)<<3))
// ---------------------------------------------------------------------------
__device__ __forceinline__ void pack_store(_Float16* __restrict__ ApN, int img,
                                           int m, int h, float v)
{
    _Float16 hi = (_Float16)v;
    _Float16 lo = (_Float16)((v - (float)hi) * LO_SCALE);
    int mt = m >> 6, r = m & 63;
    size_t base = ((size_t)(img * 16 + mt) * 8 + (h >> 6)) * 4096
                + r * 64 + ((h & 63) ^ ((r & 7) << 3));
    ApN[base] = hi;
    ApN[base + 16384] = lo;   // +4 planes
}

// ---------------------------------------------------------------------------
// Top-K gating, thread-per-element (block=1024). Matches jax.lax.top_k order.
// Level-0 blocks also zero Weff/beff for the atomic l4combine in prep.
// ---------------------------------------------------------------------------
__global__ __launch_bounds__(1024) void gate_kernel(const float* __restrict__ rg,
                                                    int* __restrict__ gidx,
                                                    float* __restrict__ gval,
                                                    float* __restrict__ Weff,
                                                    float* __restrict__ beff)
{
    const int EDAT[5] = {8, 16, 64, 256, 1024};
    const int KDAT[5] = {4, 4, 32, 32, 256};
    const int OFF[5]  = {0, 8, 24, 88, 344};
    const int level = blockIdx.x, img = blockIdx.y;
    const int E = EDAT[level], K = KDAT[level], off = OFF[level];
    __shared__ float ga[1024];
    const float* src = rg + img * 1368 + off;
    const int t = threadIdx.x;
    if (level == 0) {   // zero l4 accumulators (poisoned 0xAA each launch)
        if (t < 768) Weff[img * 768 + t] = 0.f;
        if (t < 3) beff[img * 3 + t] = 0.f;
    }
    if (t < E) ga[t] = src[t];
    __syncthreads();
    if (t < E) {
        const float v = ga[t];
        const float a = fabsf(v);
        int rank = 0;
#pragma unroll 8
        for (int j = 0; j < E; j++) {
            float aj = fabsf(ga[j]);
            rank += (aj > a) || (aj == a && j < t);
        }
        if (rank < K) {
            int base = (level * 2 + img) * 256;
            gidx[base + rank] = t;
            gval[base + rank] = v;
        }
    }
}

// ---------------------------------------------------------------------------
// Layer 0 (pack-fused): x[i,c,h] = sum_k gv[k]*sin(30*(coords·W0row+b0)) -> Ap
// ---------------------------------------------------------------------------
__global__ __launch_bounds__(256) void layer0_kernel(const float* __restrict__ coords,
                                                     const float* __restrict__ W0,
                                                     const float* __restrict__ b0,
                                                     const int* __restrict__ gidx,
                                                     const float* __restrict__ gval,
                                                     _Float16* __restrict__ ApN)
{
    const int c = blockIdx.x, img = blockIdx.y, h = threadIdx.x;
    __shared__ int gi[4];
    __shared__ float gv[4];
    if (h < 4) {
        int base = (0 * 2 + img) * 256;
        gi[h] = gidx[base + h];
        gv[h] = gval[base + h];
    }
    __syncthreads();
    const float c0 = coords[c * 2], c1 = coords[c * 2 + 1];
    float s = 0.f;
#pragma unroll
    for (int k = 0; k < 4; k++) {
        int row = h * 8 + gi[k];
        s += gv[k] * __sinf(30.f * (c0 * W0[row * 2] + c1 * W0[row * 2 + 1] + b0[row]));
    }
    pack_store(ApN, img, c, h, s);
}

// ---------------------------------------------------------------------------
// wpack body: gather active W rows, hi+lo planes, pre-swizzled tiles.
// ---------------------------------------------------------------------------
__device__ __forceinline__ void wpack_body(const float* __restrict__ W,
                                           const float* __restrict__ bias,
                                           const int* __restrict__ gidx,
                                           const float* __restrict__ gval,
                                           int level, int E, int lgK, int ntiles,
                                           _Float16* __restrict__ Bp,
                                           float* __restrict__ biasP,
                                           float* __restrict__ gvP,
                                           int ntile, int img, int sa)
{
    const int t = threadIdx.x;
    const int N = ntiles * 64;
    __shared__ int wrowS[64];
    const int base = (level * 2 + img) * 256;
    if (t < 64) {
        int n = ntile * 64 + t;
        int dd = n >> lgK, k = n & ((1 << lgK) - 1);
        int wrow = dd * E + gidx[base + k];
        wrowS[t] = wrow;
        if (sa == 0) {
            biasP[img * N + n] = bias[wrow];
            gvP[img * N + n] = gval[base + k];
        }
    }
    __syncthreads();
    const int c = t & 63, r0 = t >> 6;
    const int kk = sa * 64 + c;
    _Float16* bph = Bp + ((size_t)(img * ntiles + ntile) * 8 + sa) * 4096;
    _Float16* bpl = bph + 4 * 4096;
#pragma unroll
    for (int rr = 0; rr < 64; rr += 4) {
        int r = rr + r0;
        float v = W[(size_t)wrowS[r] * HID + kk];
        _Float16 h = (_Float16)v;
        int idx = r * 64 + (c ^ ((r & 7) << 3));
        bph[idx] = h;
        bpl[idx] = (_Float16)((v - (float)h) * LO_SCALE);
    }
}

// ---------------------------------------------------------------------------
// prep: merged wpack(level1) + wpack(level2) + parallel l4combine (atomics).
// 128 + 1024 + 48 = 1200 blocks, all only depend on gate output.
// ---------------------------------------------------------------------------
__global__ __launch_bounds__(256) void prep_kernel(const float* __restrict__ W1,
                                                   const float* __restrict__ b1,
                                                   const float* __restrict__ W2,
                                                   const float* __restrict__ b2,
                                                   const float* __restrict__ W4,
                                                   const float* __restrict__ b4,
                                                   const int* __restrict__ gidx,
                                                   const float* __restrict__ gval,
                                                   _Float16* __restrict__ Bp1,
                                                   float* __restrict__ bias1,
                                                   float* __restrict__ gv1,
                                                   _Float16* __restrict__ Bp23,
                                                   float* __restrict__ bias2,
                                                   float* __restrict__ gv2,
                                                   float* __restrict__ Weff,
                                                   float* __restrict__ beff)
{
    const int b = blockIdx.x;
    if (b < 128) {
        int ntile = b & 15, img = (b >> 4) & 1, sa = b >> 5;
        wpack_body(W1, b1, gidx, gval, 1, 16, 2, 16, Bp1, bias1, gv1, ntile, img, sa);
    } else if (b < 1152) {
        int s = b - 128;
        int ntile = s & 127, img = (s >> 7) & 1, sa = s >> 8;
        wpack_body(W2, b2, gidx, gval, 2, 64, 5, 128, Bp23, bias2, gv2, ntile, img, sa);
    } else {
        // l4combine partial: chunk ck of 32 experts -> atomicAdd into Weff/beff
        const int idx = b - 1152;            // 0..47
        const int d = idx % 3, img = (idx / 3) % 2, ck = idx / 6;
        const int t = threadIdx.x;
        __shared__ float gs[32];
        __shared__ int rows[32];
        const int base = (4 * 2 + img) * 256 + ck * 32;
        if (t < 32) {
            gs[t] = gval[base + t];
            rows[t] = (d * 1024 + gidx[base + t]) * 256;
        }
        __syncthreads();
        float acc = 0.f;
#pragma unroll 8
        for (int k = 0; k < 32; ++k)
            acc = fmaf(gs[k], W4[(size_t)rows[k] + t], acc);
        atomicAdd(&Weff[(img * 3 + d) * 256 + t], acc);
        if (t == 0) {
            float bb = 0.f;
            for (int k = 0; k < 32; ++k)
                bb += gs[k] * b4[d * 1024 + gidx[base + k]];
            atomicAdd(&beff[img * 3 + d], bb);
        }
    }
}

// ---------------------------------------------------------------------------
// standalone wpack for level 3 (must run after mid2 frees Bp23).
// ---------------------------------------------------------------------------
__global__ __launch_bounds__(256) void wpack3_kernel(const float* __restrict__ W,
                                                     const float* __restrict__ bias,
                                                     const int* __restrict__ gidx,
                                                     const float* __restrict__ gval,
                                                     _Float16* __restrict__ Bp,
                                                     float* __restrict__ biasP,
                                                     float* __restrict__ gvP)
{
    wpack_body(W, bias, gidx, gval, 3, 256, 5, 128, Bp, biasP, gvP,
               blockIdx.x, blockIdx.y, blockIdx.z);
}

// ---------------------------------------------------------------------------
// Mid-layer MFMA GEMM, split-f16, XCD-swizzled flat grid.
// 128x128 block, 4 waves of 64x64. SINGLE 64KB LDS buffer -> 2 blocks/CU.
// Per phase p (k-slice of 64): [vmcnt0+barrier: slice p resident] ->
// reads ks0 + MFMA ks0 -> reads ks1 -> barrier (all reads done) ->
// stage(p+1) into same buffer -> MFMA ks1 (hides stage issue; co-resident
// block hides the rest of the DMA).  result = acc + accL/2048.
// Epilogue fully in registers: 16-lane __shfl_xor reduce over expert groups,
// then PACK (hi/lo f16 swizzled tiles for next level) or f32 store.
// ---------------------------------------------------------------------------
template <int KGRP, int NTB, bool PACK>
__global__ __launch_bounds__(256, 1) void mid_mfma_kernel(const _Float16* __restrict__ Ap,
                                                          const _Float16* __restrict__ Bp,
                                                          const float* __restrict__ biasPp,
                                                          const float* __restrict__ gvPp,
                                                          float* __restrict__ xout,
                                                          _Float16* __restrict__ ApN)
{
    constexpr int NTBX = NTB / 8;
    const int b = blockIdx.x;
    const int q = b & 7;            // XCD
    const int j = b >> 3;
    const int mtp = j & 7;          // 128-row tile
    const int img = (j >> 3) & 1;
    const int ntl = j >> 4;
    const int nt = q * NTBX + ntl;  // 128-col tile

    const int tid = threadIdx.x;
    const int wave = tid >> 6, lane = tid & 63;
    const int wm = wave & 1, wn = wave >> 1;
    const int l15 = lane & 15, lhi = lane >> 4;

    __shared__ __align__(16) char lds[65536];   // ONE k-slice: Ah|Al|Bh|Bl 16KB each

    const int ntiles = NTB * 2;
    const int N = NTB * 128;
    const _Float16* ag = Ap + ((size_t)(img * 16 + mtp * 2) * 8) * 4096;
    const _Float16* bg = Bp + ((size_t)(img * ntiles + nt * 2) * 8) * 4096;

    const _Float16* sbase = (wave & 2) ? bg : ag;
    const int planeAdd = (wave & 1) ? 4 : 0;
    auto stage = [&](int p) {
#pragma unroll
        for (int qq = 0; qq < 16; ++qq) {
            const _Float16* g = sbase + (size_t)(qq >> 3) * 32768
                              + (planeAdd + p) * 4096 + (qq & 7) * 512 + lane * 8;
            __builtin_amdgcn_global_load_lds((gvoid*)g,
                (lvoid*)(lds + wave * 16384 + qq * 1024), 16, 0, 0);
        }
    };

    f32x4 acc[4][4], accL[4][4];
#pragma unroll
    for (int mi = 0; mi < 4; mi++)
#pragma unroll
        for (int ni = 0; ni < 4; ni++) { acc[mi][ni] = (f32x4)0.f; accL[mi][ni] = (f32x4)0.f; }

    stage(0);

#pragma unroll
    for (int p = 0; p < 4; ++p) {
        asm volatile("s_waitcnt vmcnt(0)" ::: "memory");
        __syncthreads();                        // slice p resident
        f16x8 ah[2][4], al[2][4], bh[2][4], bl[2][4];
        // ---- ks=0 frags + MFMA ----
#pragma unroll
        for (int mi = 0; mi < 4; ++mi) {
            int row = wm * 64 + mi * 16 + l15;
            int off = (row >> 6) * 8192 + (row & 63) * 128 + ((lhi ^ (row & 7)) * 16);
            ah[0][mi] = *(const f16x8*)(lds + off);
            al[0][mi] = *(const f16x8*)(lds + 16384 + off);
        }
#pragma unroll
        for (int ni = 0; ni < 4; ++ni) {
            int row = wn * 64 + ni * 16 + l15;
            int off = (row >> 6) * 8192 + (row & 63) * 128 + ((lhi ^ (row & 7)) * 16);
            bh[0][ni] = *(const f16x8*)(lds + 32768 + off);
            bl[0][ni] = *(const f16x8*)(lds + 49152 + off);
        }
#pragma unroll
        for (int mi = 0; mi < 4; ++mi)
#pragma unroll
            for (int ni = 0; ni < 4; ++ni)
                acc[mi][ni] = __builtin_amdgcn_mfma_f32_16x16x32_f16(ah[0][mi], bh[0][ni],
                                                                     acc[mi][ni], 0, 0, 0);
#pragma unroll
        for (int mi = 0; mi < 4; ++mi)
#pragma unroll
            for (int ni = 0; ni < 4; ++ni)
                accL[mi][ni] = __builtin_amdgcn_mfma_f32_16x16x32_f16(al[0][mi], bh[0][ni],
                                                                      accL[mi][ni], 0, 0, 0);
#pragma unroll
        for (int mi = 0; mi < 4; ++mi)
#pragma unroll
            for (int ni = 0; ni < 4; ++ni)
                accL[mi][ni] = __builtin_amdgcn_mfma_f32_16x16x32_f16(ah[0][mi], bl[0][ni],
                                                                      accL[mi][ni], 0, 0, 0);
        // ---- ks=1 frags ----
#pragma unroll
        for (int mi = 0; mi < 4; ++mi) {
            int row = wm * 64 + mi * 16 + l15;
            int off = (row >> 6) * 8192 + (row & 63) * 128 + ((((lhi + 4)) ^ (row & 7)) * 16);
            ah[1][mi] = *(const f16x8*)(lds + off);
            al[1][mi] = *(const f16x8*)(lds + 16384 + off);
        }
#pragma unroll
        for (int ni = 0; ni < 4; ++ni) {
            int row = wn * 64 + ni * 16 + l15;
            int off = (row >> 6) * 8192 + (row & 63) * 128 + ((((lhi + 4)) ^ (row & 7)) * 16);
            bh[1][ni] = *(const f16x8*)(lds + 32768 + off);
            bl[1][ni] = *(const f16x8*)(lds + 49152 + off);
        }
        __syncthreads();                        // all waves' slice-p reads done
        if (p < 3) stage(p + 1);                // overwrite buffer; lands by next drain
        // ---- ks=1 MFMA (covers stage issue) ----
#pragma unroll
        for (int mi = 0; mi < 4; ++mi)
#pragma unroll
            for (int ni = 0; ni < 4; ++ni)
                acc[mi][ni] = __builtin_amdgcn_mfma_f32_16x16x32_f16(ah[1][mi], bh[1][ni],
                                                                     acc[mi][ni], 0, 0, 0);
#pragma unroll
        for (int mi = 0; mi < 4; ++mi)
#pragma unroll
            for (int ni = 0; ni < 4; ++ni)
                accL[mi][ni] = __builtin_amdgcn_mfma_f32_16x16x32_f16(al[1][mi], bh[1][ni],
                                                                      accL[mi][ni], 0, 0, 0);
#pragma unroll
        for (int mi = 0; mi < 4; ++mi)
#pragma unroll
            for (int ni = 0; ni < 4; ++ni)
                accL[mi][ni] = __builtin_amdgcn_mfma_f32_16x16x32_f16(ah[1][mi], bl[1][ni],
                                                                      accL[mi][ni], 0, 0, 0);
    }

    // ---- in-register epilogue: combine, bias+sin+gate, shuffle-reduce, store ----
    const int mbase = mtp * 128 + wm * 64;
    if (KGRP == 32) {
        float red[4][2][4];
#pragma unroll
        for (int mi = 0; mi < 4; ++mi)
#pragma unroll
            for (int pp = 0; pp < 2; ++pp)
#pragma unroll
                for (int r = 0; r < 4; ++r) red[mi][pp][r] = 0.f;
#pragma unroll
        for (int ni = 0; ni < 4; ++ni) {
            int gn = nt * 128 + wn * 64 + ni * 16 + l15;
            float bv = biasPp[img * N + gn];
            float gvv = gvPp[img * N + gn];
#pragma unroll
            for (int mi = 0; mi < 4; ++mi)
#pragma unroll
                for (int r = 0; r < 4; ++r) {
                    float val = acc[mi][ni][r] + accL[mi][ni][r] * LO_INV;
                    red[mi][ni >> 1][r] += gvv * __sinf(30.f * (val + bv));
                }
        }
#pragma unroll
        for (int mask = 1; mask <= 8; mask <<= 1)
#pragma unroll
            for (int mi = 0; mi < 4; ++mi)
#pragma unroll
                for (int pp = 0; pp < 2; ++pp)
#pragma unroll
                    for (int r = 0; r < 4; ++r)
                        red[mi][pp][r] += __shfl_xor(red[mi][pp][r], mask);
        if (l15 == 0) {
#pragma unroll
            for (int mi = 0; mi < 4; ++mi)
#pragma unroll
                for (int pp = 0; pp < 2; ++pp)
#pragma unroll
                    for (int r = 0; r < 4; ++r) {
                        int m = mbase + mi * 16 + lhi * 4 + r;
                        int h = nt * 4 + wn * 2 + pp;
                        if (PACK) pack_store(ApN, img, m, h, red[mi][pp][r]);
                        else xout[((size_t)img * NC + m) * HID + h] = red[mi][pp][r];
                    }
        }
    } else {
        float e[4][4][4];
#pragma unroll
        for (int ni = 0; ni < 4; ++ni) {
            int gn = nt * 128 + wn * 64 + ni * 16 + l15;
            float bv = biasPp[img * N + gn];
            float gvv = gvPp[img * N + gn];
#pragma unroll
            for (int mi = 0; mi < 4; ++mi)
#pragma unroll
                for (int r = 0; r < 4; ++r) {
                    float val = acc[mi][ni][r] + accL[mi][ni][r] * LO_INV;
                    e[mi][ni][r] = gvv * __sinf(30.f * (val + bv));
                }
        }
#pragma unroll
        for (int mask = 1; mask <= 2; mask <<= 1)
#pragma unroll
            for (int mi = 0; mi < 4; ++mi)
#pragma unroll
                for (int ni = 0; ni < 4; ++ni)
#pragma unroll
                    for (int r = 0; r < 4; ++r)
                        e[mi][ni][r] += __shfl_xor(e[mi][ni][r], mask);
        if ((l15 & 3) == 0) {
#pragma unroll
            for (int mi = 0; mi < 4; ++mi)
#pragma unroll
                for (int ni = 0; ni < 4; ++ni)
#pragma unroll
                    for (int r = 0; r < 4; ++r) {
                        int m = mbase + mi * 16 + lhi * 4 + r;
                        int h = nt * 32 + wn * 16 + ni * 4 + (l15 >> 2);
                        if (PACK) pack_store(ApN, img, m, h, e[mi][ni][r]);
                        else xout[((size_t)img * NC + m) * HID + h] = e[mi][ni][r];
                    }
        }
    }
}

// ---------------------------------------------------------------------------
// Layer 4 apply: out[i,c,d] = x[i,c,:]·Weff[i,d,:] + beff[i,d]
// ---------------------------------------------------------------------------
__global__ __launch_bounds__(256) void l4apply_kernel(const float* __restrict__ x_in,
                                                      const float* __restrict__ Weff,
                                                      const float* __restrict__ beff,
                                                      float* __restrict__ out)
{
    const int img = blockIdx.y;
    const int c = blockIdx.x * 256 + threadIdx.x;
    __shared__ float ws[3][256];
    __shared__ float bs[3];
    const int t = threadIdx.x;
    if (t < 192) {
        int d = t / 64, k4 = t % 64;
        *(float4*)&ws[d][k4 * 4] = *(const float4*)(Weff + (img * 3 + d) * 256 + k4 * 4);
    }
    if (t < 3) bs[t] = beff[img * 3 + t];
    __syncthreads();
    const float* xb = x_in + ((size_t)img * NC + c) * HID;
    float a0 = 0.f, a1 = 0.f, a2 = 0.f;
#pragma unroll 4
    for (int k = 0; k < 256; k += 4) {
        const float4 xv = *(const float4*)(xb + k);
        const float4 w0 = *(const float4*)&ws[0][k];
        const float4 w1 = *(const float4*)&ws[1][k];
        const float4 w2 = *(const float4*)&ws[2][k];
        a0 += xv.x * w0.x + xv.y * w0.y + xv.z * w0.z + xv.w * w0.w;
        a1 += xv.x * w1.x + xv.y * w1.y + xv.z * w1.z + xv.w * w1.w;
        a2 += xv.x * w2.x + xv.y * w2.y + xv.z * w2.z + xv.w * w2.w;
    }
    float* o = out + ((size_t)img * NC + c) * 3;
    o[0] = a0 + bs[0];
    o[1] = a1 + bs[1];
    o[2] = a2 + bs[2];
}

// ---------------------------------------------------------------------------
extern "C" void kernel_launch(void* const* d_in, const int* in_sizes, int n_in,
                              void* d_out, int out_size, void* d_ws, size_t ws_size,
                              hipStream_t stream)
{
    const float* rg     = (const float*)d_in[0];
    const float* coords = (const float*)d_in[1];
    const float* W0 = (const float*)d_in[2];
    const float* b0 = (const float*)d_in[3];
    const float* W1 = (const float*)d_in[4];
    const float* b1 = (const float*)d_in[5];
    const float* W2 = (const float*)d_in[6];
    const float* b2 = (const float*)d_in[7];
    const float* W3 = (const float*)d_in[8];
    const float* b3 = (const float*)d_in[9];
    const float* W4 = (const float*)d_in[10];
    const float* b4 = (const float*)d_in[11];
    float* out = (float*)d_out;

    char* ws = (char*)d_ws;
    int*      gidx  = (int*)(ws + OFF_GIDX);
    float*    gval  = (float*)(ws + OFF_GVAL);
    float*    bias1 = (float*)(ws + OFF_B1);
    float*    gv1   = (float*)(ws + OFF_G1);
    float*    bias2 = (float*)(ws + OFF_B2);
    float*    gv2   = (float*)(ws + OFF_G2);
    float*    bias3 = (float*)(ws + OFF_B3);
    float*    gv3   = (float*)(ws + OFF_G3);
    float*    Weff  = (float*)(ws + OFF_WEFF);
    float*    beff  = (float*)(ws + OFF_BEFF);
    _Float16* ApA   = (_Float16*)(ws + OFF_APA);
    _Float16* ApB   = (_Float16*)(ws + OFF_APB);
    _Float16* Bp1   = (_Float16*)(ws + OFF_BP1);
    float*    xB    = (float*)(ws + OFF_BP1);    // alias: Bp1 dead after mid1
    _Float16* Bp23  = (_Float16*)(ws + OFF_BP23);

    gate_kernel<<<dim3(5, 2), 1024, 0, stream>>>(rg, gidx, gval, Weff, beff);
    prep_kernel<<<1200, 256, 0, stream>>>(W1, b1, W2, b2, W4, b4, gidx, gval,
                                          Bp1, bias1, gv1, Bp23, bias2, gv2, Weff, beff);
    layer0_kernel<<<dim3(NC, NI), 256, 0, stream>>>(coords, W0, b0, gidx, gval, ApA);

    // level 1: E=16, K=4 -> packed ApB
    mid_mfma_kernel<4, 8, true><<<128, 256, 0, stream>>>(ApA, Bp1, bias1, gv1, nullptr, ApB);
    // level 2: E=64, K=32 -> packed ApA
    mid_mfma_kernel<32, 64, true><<<1024, 256, 0, stream>>>(ApB, Bp23, bias2, gv2, nullptr, ApA);
    // level 3 weights (Bp23 free after mid2)
    wpack3_kernel<<<dim3(128, 2, 4), 256, 0, stream>>>(W3, b3, gidx, gval, Bp23, bias3, gv3);
    // level 3: E=256, K=32 -> f32 xB (aliases Bp1)
    mid_mfma_kernel<32, 64, false><<<1024, 256, 0, stream>>>(ApA, Bp23, bias3, gv3, xB, nullptr);

    l4apply_kernel<<<dim3(4, 2), 256, 0, stream>>>(xB, Weff, beff, out);
}